// Round 8
// baseline (291.657 us; speedup 1.0000x reference)
//
#include <hip/hip_runtime.h>
#include <hip/hip_bf16.h>

#define NT 4096   // tokens
#define CD 768    // channels
#define NH 12     // heads
#define HD 64     // head dim
#define CQ 2304   // 3*CD

typedef __bf16 bf;
typedef __bf16 v8bf __attribute__((ext_vector_type(8)));
typedef __bf16 v4bf __attribute__((ext_vector_type(4)));
typedef float  v4f  __attribute__((ext_vector_type(4)));

// async global->LDS, 16B per lane; LDS dest must be wave-uniform base + lane*16
__device__ __forceinline__ void gld16(const bf* g, bf* l) {
  __builtin_amdgcn_global_load_lds(
      (__attribute__((address_space(1))) void*)g,
      (__attribute__((address_space(3))) void*)l,
      16, 0, 0);
}

__device__ __forceinline__ float fexp2(float x) {
#if defined(__HIP_DEVICE_COMPILE__)
  return __builtin_amdgcn_exp2f(x);
#else
  return x;  // host pass never executes device code
#endif
}

// ---------- merged prep: fp32->bf16 cast of x  +  transpose-cast of both weights ----------
// blocks [0,3072): cast x (256 float4 each)
// blocks [3072,4800): transpose wqkv 768x2304 -> WqkvT 2304x768
// blocks [4800,5376): transpose wproj 768x768 -> WpT 768x768
__global__ __launch_bounds__(256) void prep(
    const float* __restrict__ x, const float* __restrict__ wqkv,
    const float* __restrict__ wproj, bf* __restrict__ Xb,
    bf* __restrict__ WqkvT, bf* __restrict__ WpT) {
  __shared__ float tile[32][33];
  const int b = blockIdx.x, tid = threadIdx.x;
  if (b < 3072) {
    const int i = b * 256 + tid;  // n4 = 786432 = 3072*256 exactly
    const float4 v = ((const float4*)x)[i];
    bf o4[4] = {(bf)v.x, (bf)v.y, (bf)v.z, (bf)v.w};
    ((ushort4*)Xb)[i] = *(const ushort4*)o4;
    return;
  }
  const float* in;
  bf* out;
  int rows, cols, c0, r0;
  if (b < 4800) {
    const int t = b - 3072;           // 72 col-blocks x 24 row-blocks
    in = wqkv; out = WqkvT; rows = CD; cols = CQ;
    c0 = (t % 72) * 32; r0 = (t / 72) * 32;
  } else {
    const int t = b - 4800;           // 24 x 24
    in = wproj; out = WpT; rows = CD; cols = CD;
    c0 = (t % 24) * 32; r0 = (t / 24) * 32;
  }
  const int tx = tid & 31, ty = tid >> 5;  // 32 x 8
#pragma unroll
  for (int j = 0; j < 32; j += 8)
    tile[ty + j][tx] = in[(size_t)(r0 + ty + j) * cols + (c0 + tx)];
  __syncthreads();
#pragma unroll
  for (int j = 0; j < 32; j += 8)
    out[(size_t)(c0 + ty + j) * rows + (r0 + tx)] = (bf)tile[tx][ty + j];
}

// ------------- QKV GEMM: Xb[4096x768] * WqkvT[2304x768]^T, scatter epilogue -------------
__global__ __launch_bounds__(256) void gemm_qkv(
    const bf* __restrict__ A, const bf* __restrict__ Bt,
    bf* __restrict__ Qb, bf* __restrict__ Kb, bf* __restrict__ Vtb) {
  __shared__ __align__(16) bf As[128 * 32];
  __shared__ __align__(16) bf Bs[128 * 32];
  const int tid = threadIdx.x;
  const int lane = tid & 63, wave = tid >> 6;
  const int lane15 = lane & 15, quad = lane >> 4;
  const int waveM = wave & 1, waveN = wave >> 1;
  const int bm = blockIdx.x * 128;
  const int bn = blockIdx.y * 128;

  v4f acc[4][4];
#pragma unroll
  for (int i = 0; i < 4; ++i)
#pragma unroll
    for (int j = 0; j < 4; ++j) acc[i][j] = (v4f){0.f, 0.f, 0.f, 0.f};

  for (int k0 = 0; k0 < CD; k0 += 32) {
#pragma unroll
    for (int p = 0; p < 2; ++p) {
      const int t = tid + p * 256;
      const int r = t >> 2, c = (t & 3) * 8;
      gld16(A + (size_t)(bm + r) * CD + k0 + c, As + t * 8);
    }
#pragma unroll
    for (int p = 0; p < 2; ++p) {
      const int t = tid + p * 256;
      const int r = t >> 2, c = (t & 3) * 8;
      gld16(Bt + (size_t)(bn + r) * CD + k0 + c, Bs + t * 8);
    }
    asm volatile("s_waitcnt vmcnt(0)" ::: "memory");
    __syncthreads();

    v8bf af[4], bfr[4];
#pragma unroll
    for (int mt = 0; mt < 4; ++mt)
      af[mt] = *(const v8bf*)(As + (waveM * 64 + mt * 16 + lane15) * 32 + quad * 8);
#pragma unroll
    for (int nt = 0; nt < 4; ++nt)
      bfr[nt] = *(const v8bf*)(Bs + (waveN * 64 + nt * 16 + lane15) * 32 + quad * 8);
#pragma unroll
    for (int mt = 0; mt < 4; ++mt)
#pragma unroll
      for (int nt = 0; nt < 4; ++nt)
        acc[mt][nt] = __builtin_amdgcn_mfma_f32_16x16x32_bf16(af[mt], bfr[nt], acc[mt][nt], 0, 0, 0);
    __syncthreads();
  }

  const float QSCALE = 0.125f * 1.4426950408889634f;  // fold D^-0.5 * log2(e)
#pragma unroll
  for (int mt = 0; mt < 4; ++mt) {
    const int rowB = bm + waveM * 64 + mt * 16 + quad * 4;
#pragma unroll
    for (int nt = 0; nt < 4; ++nt) {
      const int col = bn + waveN * 64 + nt * 16 + lane15;
      const int s = col / CD;
      const int rem = col - s * CD;
      const int h = rem >> 6, d = rem & 63;
      if (s == 2) {
        // V^T: lane owns 4 consecutive rows at fixed column -> one 8B store
        bf vp[4];
#pragma unroll
        for (int i = 0; i < 4; ++i) vp[i] = (bf)acc[mt][nt][i];
        *(uint2*)(Vtb + ((size_t)h * HD + d) * NT + rowB) = *(const uint2*)vp;
      } else {
#pragma unroll
        for (int i = 0; i < 4; ++i) {
          const float v = acc[mt][nt][i];
          const int row = rowB + i;
          if (s == 0) Qb[((size_t)h * NT + row) * HD + d] = (bf)(v * QSCALE);
          else        Kb[((size_t)h * NT + row) * HD + d] = (bf)v;
        }
      }
    }
  }
}

// ------------- attention: block = 1 head x 64 Q rows; wave = 32-key quarter x ALL 64 Q rows ---
// max-free softmax; P stays in registers (key-permuted V LDS layout matches P's slot order);
// register double-buffer: next tile's global loads issued before compute, hidden behind it.
__global__ __launch_bounds__(256, 3) void attn(
    const bf* __restrict__ Qb, const bf* __restrict__ Kb,
    const bf* __restrict__ Vtb, bf* __restrict__ Ob) {
  __shared__ __align__(16) char smem[35840];
  bf* Ks = (bf*)smem;              // [128 keys][64 dims pad 72]  = 18432 B
  bf* Vs = (bf*)(smem + 18432);    // [64 dims][128 keys pad 136] = 17408 B (permuted key order)
  float* Red = (float*)smem;       // epilogue reuse: 8 regions x 1024 f + lsum

  const int h = blockIdx.y;
  const int q0 = blockIdx.x * 64;
  const int tid = threadIdx.x;
  const int wave = tid >> 6, lane = tid & 63;
  const int lane15 = lane & 15, quad = lane >> 4;

  const bf* Kh = Kb + (size_t)h * NT * HD;
  const bf* Vh = Vtb + (size_t)h * HD * NT;

  // per-thread staging geometry (constant across iterations)
  const int rK = tid >> 1;              // K: row (2 threads/row), 4 rows apart per p
  const int cK = (tid & 1) * 32;        // ...wait: recompute below per-p (keep r/c from u)
  (void)rK; (void)cK;

  // Q fragments for all 4 sub-tiles (B-operand: n=lane15=Q row, k=quad*8+j=dim)
  v8bf aQ[4][2];
#pragma unroll
  for (int sub = 0; sub < 4; ++sub) {
    const int qrow = q0 + sub * 16 + lane15;
    aQ[sub][0] = *(const v8bf*)(Qb + ((size_t)h * NT + qrow) * HD + quad * 8);
    aQ[sub][1] = *(const v8bf*)(Qb + ((size_t)h * NT + qrow) * HD + 32 + quad * 8);
  }

  v4f o[4][4];                 // [sub][dt], C-layout: col=lane15=dim, row=quad*4+i=Q row
#pragma unroll
  for (int sub = 0; sub < 4; ++sub)
#pragma unroll
    for (int dt = 0; dt < 4; ++dt) o[sub][dt] = (v4f){0.f, 0.f, 0.f, 0.f};
  float lsum[4] = {0.f, 0.f, 0.f, 0.f};

  // prefetch registers for the next tile
  uint4 kreg[4], vreg[4];
#pragma unroll
  for (int p = 0; p < 4; ++p) {
    const int u = tid + p * 256;
    const int r = u >> 3, c = (u & 7) * 8;
    kreg[p] = *(const uint4*)(Kh + (size_t)r * HD + c);          // kt = 0
    const int d = u >> 4, cv = (u & 15) * 8;
    vreg[p] = *(const uint4*)(Vh + (size_t)d * NT + cv);         // kt = 0
  }

  for (int kt = 0; kt < NT; kt += 128) {
    // write previous prefetch to LDS
#pragma unroll
    for (int p = 0; p < 4; ++p) {
      const int u = tid + p * 256;
      const int r = u >> 3, c = (u & 7) * 8;
      *(uint4*)(Ks + r * 72 + c) = kreg[p];
    }
#pragma unroll
    for (int p = 0; p < 4; ++p) {
      const int u = tid + p * 256;
      const int d = u >> 4, c = (u & 15) * 8;
      const int t32 = c >> 5, g = (c & 31) >> 3;
      const int pa = ((g & 1) << 4) | ((g >> 1) << 2);
      bf* dst = Vs + d * 136 + t32 * 32 + pa;
      *(uint2*)dst       = make_uint2(vreg[p].x, vreg[p].y);
      *(uint2*)(dst + 8) = make_uint2(vreg[p].z, vreg[p].w);
    }
    __syncthreads();

    // issue next tile's global loads now; results consumed at next iteration's LDS write
    const int ktn = (kt + 128) & (NT - 1);
#pragma unroll
    for (int p = 0; p < 4; ++p) {
      const int u = tid + p * 256;
      const int r = u >> 3, c = (u & 7) * 8;
      kreg[p] = *(const uint4*)(Kh + (size_t)(ktn + r) * HD + c);
      const int d = u >> 4, cv = (u & 15) * 8;
      vreg[p] = *(const uint4*)(Vh + (size_t)d * NT + ktn + cv);
    }

    // S^T = K Q^T on this wave's 32 keys (2 chunks of 16) x all 64 Q rows
    v4bf aPlo[4], aPhi[4];
#pragma unroll
    for (int e = 0; e < 2; ++e) {
      const bf* krow = Ks + ((wave * 2 + e) * 16 + lane15) * 72;
      const v8bf bk0 = *(const v8bf*)(krow + quad * 8);
      const v8bf bk1 = *(const v8bf*)(krow + 32 + quad * 8);
#pragma unroll
      for (int sub = 0; sub < 4; ++sub) {
        v4f z = (v4f){0.f, 0.f, 0.f, 0.f};
        z = __builtin_amdgcn_mfma_f32_16x16x32_bf16(bk0, aQ[sub][0], z, 0, 0, 0);
        z = __builtin_amdgcn_mfma_f32_16x16x32_bf16(bk1, aQ[sub][1], z, 0, 0, 0);
        v4bf p4;
#pragma unroll
        for (int r = 0; r < 4; ++r) {
          const float p = fexp2(z[r]);
          lsum[sub] += p;
          p4[r] = (bf)p;
        }
        if (e == 0) aPlo[sub] = p4; else aPhi[sub] = p4;
      }
    }

    // O += P V over this wave's 32 keys: one x32 MFMA per (sub,dt).
    // A slot (q,j) holds key j<4?4q+j:16+4q+j-4 == V's LDS position order.
#pragma unroll
    for (int dt = 0; dt < 4; ++dt) {
      const v8bf bv = *(const v8bf*)(Vs + (dt * 16 + lane15) * 136 + wave * 32 + quad * 8);
#pragma unroll
      for (int sub = 0; sub < 4; ++sub) {
        const v8bf aP8 = __builtin_shufflevector(aPlo[sub], aPhi[sub], 0, 1, 2, 3, 4, 5, 6, 7);
        o[sub][dt] = __builtin_amdgcn_mfma_f32_16x16x32_bf16(aP8, bv, o[sub][dt], 0, 0, 0);
      }
    }
    __syncthreads();
  }

  // quad-reduce denoms: lane then holds denom partial (this wave's 32 keys) for Qrow=lane15
#pragma unroll
  for (int sub = 0; sub < 4; ++sub) {
    lsum[sub] += __shfl_xor(lsum[sub], 16, 64);
    lsum[sub] += __shfl_xor(lsum[sub], 32, 64);
  }

  // cross-wave combine, two phases of 2 subs (LDS budget). Region rw=wave*2+sl:
  // [dt][col=lane15][row] = 1024 floats; lsum at float offset 8192.
#pragma unroll
  for (int sp = 0; sp < 2; ++sp) {
    __syncthreads();
#pragma unroll
    for (int sl = 0; sl < 2; ++sl) {
      const int s = sp * 2 + sl;
      float* reg = Red + (wave * 2 + sl) * 1024;
#pragma unroll
      for (int dt = 0; dt < 4; ++dt)
        *(v4f*)(reg + dt * 256 + lane15 * 16 + quad * 4) = o[s][dt];
      if (quad == 0) Red[8192 + (wave * 2 + sl) * 16 + lane15] = lsum[s];
    }
    __syncthreads();
    const int wlo = sp * 2;  // phase 0: waves 0,1 reduce subs 0,1; phase 1: waves 2,3 -> subs 2,3
    if (wave == wlo || wave == wlo + 1) {
      const int sl = wave - wlo;
      const int s = sp * 2 + sl;
      float den = 0.f;
#pragma unroll
      for (int wv = 0; wv < 4; ++wv) den += Red[8192 + (wv * 2 + sl) * 16 + lane15];
      const float linv = 1.f / den;  // indexed by Qrow-within-sub = lane15
#pragma unroll
      for (int dt = 0; dt < 4; ++dt) {
        v4f sum = (v4f){0.f, 0.f, 0.f, 0.f};
#pragma unroll
        for (int wv = 0; wv < 4; ++wv)
          sum += *(const v4f*)(Red + (wv * 2 + sl) * 1024 + dt * 256 + lane15 * 16 + quad * 4);
#pragma unroll
        for (int i = 0; i < 4; ++i) {
          const float linv_i = __shfl(linv, quad * 4 + i, 64);
          const int row = q0 + s * 16 + quad * 4 + i;
          Ob[(size_t)row * CD + h * HD + dt * 16 + lane15] = (bf)(sum[i] * linv_i);
        }
      }
    }
  }
}

// ------------- proj GEMM: Ob[4096x768] * WpT[768x768]^T + bias -> out fp32 -------------
__global__ __launch_bounds__(256) void gemm_proj(
    const bf* __restrict__ A, const bf* __restrict__ Bt,
    const float* __restrict__ bias, float* __restrict__ out) {
  __shared__ __align__(16) bf As[128 * 32];
  __shared__ __align__(16) bf Bs[128 * 32];
  const int tid = threadIdx.x;
  const int lane = tid & 63, wave = tid >> 6;
  const int lane15 = lane & 15, quad = lane >> 4;
  const int waveM = wave & 1, waveN = wave >> 1;
  const int bm = blockIdx.x * 128;
  const int bn = blockIdx.y * 128;

  v4f acc[4][4];
#pragma unroll
  for (int i = 0; i < 4; ++i)
#pragma unroll
    for (int j = 0; j < 4; ++j) acc[i][j] = (v4f){0.f, 0.f, 0.f, 0.f};

  for (int k0 = 0; k0 < CD; k0 += 32) {
#pragma unroll
    for (int p = 0; p < 2; ++p) {
      const int t = tid + p * 256;
      const int r = t >> 2, c = (t & 3) * 8;
      gld16(A + (size_t)(bm + r) * CD + k0 + c, As + t * 8);
    }
#pragma unroll
    for (int p = 0; p < 2; ++p) {
      const int t = tid + p * 256;
      const int r = t >> 2, c = (t & 3) * 8;
      gld16(Bt + (size_t)(bn + r) * CD + k0 + c, Bs + t * 8);
    }
    asm volatile("s_waitcnt vmcnt(0)" ::: "memory");
    __syncthreads();

    v8bf af[4], bfr[4];
#pragma unroll
    for (int mt = 0; mt < 4; ++mt)
      af[mt] = *(const v8bf*)(As + (waveM * 64 + mt * 16 + lane15) * 32 + quad * 8);
#pragma unroll
    for (int nt = 0; nt < 4; ++nt)
      bfr[nt] = *(const v8bf*)(Bs + (waveN * 64 + nt * 16 + lane15) * 32 + quad * 8);
#pragma unroll
    for (int mt = 0; mt < 4; ++mt)
#pragma unroll
      for (int nt = 0; nt < 4; ++nt)
        acc[mt][nt] = __builtin_amdgcn_mfma_f32_16x16x32_bf16(af[mt], bfr[nt], acc[mt][nt], 0, 0, 0);
    __syncthreads();
  }

#pragma unroll
  for (int mt = 0; mt < 4; ++mt) {
    const int rowB = bm + waveM * 64 + mt * 16 + quad * 4;
#pragma unroll
    for (int nt = 0; nt < 4; ++nt) {
      const int col = bn + waveN * 64 + nt * 16 + lane15;
      const float bcol = bias[col];
#pragma unroll
      for (int i = 0; i < 4; ++i)
        out[(size_t)(rowB + i) * CD + col] = acc[mt][nt][i] + bcol;
    }
  }
}

extern "C" void kernel_launch(void* const* d_in, const int* in_sizes, int n_in,
                              void* d_out, int out_size, void* d_ws, size_t ws_size,
                              hipStream_t stream) {
  const float* x     = (const float*)d_in[0];   // [4096][768] fp32
  const float* wqkv  = (const float*)d_in[1];   // [768][2304] fp32
  const float* wproj = (const float*)d_in[2];   // [768][768]  fp32
  const float* bproj = (const float*)d_in[3];   // [768]       fp32
  float* out = (float*)d_out;                   // [4096][768] fp32

  bf* ws    = (bf*)d_ws;
  bf* Xb    = ws;  ws += (size_t)NT * CD;        // [4096][768] bf16
  bf* WqkvT = ws;  ws += (size_t)CQ * CD;        // [2304][768]
  bf* WpT   = ws;  ws += (size_t)CD * CD;        // [768][768]
  bf* Qb    = ws;  ws += (size_t)NH * NT * HD;   // [h][n][d], pre-scaled by 0.125*log2e
  bf* Kb    = ws;  ws += (size_t)NH * NT * HD;   // [h][n][d]
  bf* Vtb   = ws;  ws += (size_t)NH * NT * HD;   // [h][d][n]
  bf* Ob    = ws;  ws += (size_t)NT * CD;        // [n][h*64+d]

  prep<<<5376, 256, 0, stream>>>(x, wqkv, wproj, Xb, WqkvT, WpT);
  gemm_qkv<<<dim3(NT / 128, CQ / 128), 256, 0, stream>>>(Xb, WqkvT, Qb, Kb, Vtb);
  attn<<<dim3(NT / 64, NH), 256, 0, stream>>>(Qb, Kb, Vtb, Ob);
  gemm_proj<<<dim3(NT / 128, CD / 128), 256, 0, stream>>>(Ob, WpT, bproj, out);
}

// Round 9
// 179.996 us; speedup vs baseline: 1.6204x; 1.6204x over previous
//
#include <hip/hip_runtime.h>
#include <hip/hip_bf16.h>

#define NT 4096   // tokens
#define CD 768    // channels
#define NH 12     // heads
#define HD 64     // head dim
#define CQ 2304   // 3*CD

typedef __bf16 bf;
typedef __bf16 v8bf __attribute__((ext_vector_type(8)));
typedef __bf16 v4bf __attribute__((ext_vector_type(4)));
typedef float  v4f  __attribute__((ext_vector_type(4)));

// async global->LDS, 16B per lane; LDS dest is wave-uniform base + lane*16
__device__ __forceinline__ void gld16(const bf* g, bf* l) {
  __builtin_amdgcn_global_load_lds(
      (__attribute__((address_space(1))) void*)g,
      (__attribute__((address_space(3))) void*)l,
      16, 0, 0);
}

__device__ __forceinline__ float fexp2(float x) {
#if defined(__HIP_DEVICE_COMPILE__)
  return __builtin_amdgcn_exp2f(x);
#else
  return x;  // host pass never executes device code
#endif
}

// ---------- merged prep: fp32->bf16 cast of x  +  transpose-cast of both weights ----------
__global__ __launch_bounds__(256) void prep(
    const float* __restrict__ x, const float* __restrict__ wqkv,
    const float* __restrict__ wproj, bf* __restrict__ Xb,
    bf* __restrict__ WqkvT, bf* __restrict__ WpT) {
  __shared__ float tile[32][33];
  const int b = blockIdx.x, tid = threadIdx.x;
  if (b < 3072) {
    const int i = b * 256 + tid;  // n4 = 786432 = 3072*256 exactly
    const float4 v = ((const float4*)x)[i];
    bf o4[4] = {(bf)v.x, (bf)v.y, (bf)v.z, (bf)v.w};
    ((ushort4*)Xb)[i] = *(const ushort4*)o4;
    return;
  }
  const float* in;
  bf* out;
  int rows, cols, c0, r0;
  if (b < 4800) {
    const int t = b - 3072;           // 72 col-blocks x 24 row-blocks
    in = wqkv; out = WqkvT; rows = CD; cols = CQ;
    c0 = (t % 72) * 32; r0 = (t / 72) * 32;
  } else {
    const int t = b - 4800;           // 24 x 24
    in = wproj; out = WpT; rows = CD; cols = CD;
    c0 = (t % 24) * 32; r0 = (t / 24) * 32;
  }
  const int tx = tid & 31, ty = tid >> 5;  // 32 x 8
#pragma unroll
  for (int j = 0; j < 32; j += 8)
    tile[ty + j][tx] = in[(size_t)(r0 + ty + j) * cols + (c0 + tx)];
  __syncthreads();
#pragma unroll
  for (int j = 0; j < 32; j += 8)
    out[(size_t)(c0 + ty + j) * rows + (r0 + tx)] = (bf)tile[tx][ty + j];
}

// ------------- QKV GEMM: Xb[4096x768] * WqkvT[2304x768]^T, scatter epilogue -------------
// V is written TRANSPOSED and with the per-32-key PV slot permutation baked in:
// within each 32-key group, position q*8+j holds key (j<4 ? 4q+j : 16+4q+(j-4)).
__global__ __launch_bounds__(256) void gemm_qkv(
    const bf* __restrict__ A, const bf* __restrict__ Bt,
    bf* __restrict__ Qb, bf* __restrict__ Kb, bf* __restrict__ Vtb) {
  __shared__ __align__(16) bf As[128 * 32];
  __shared__ __align__(16) bf Bs[128 * 32];
  const int tid = threadIdx.x;
  const int lane = tid & 63, wave = tid >> 6;
  const int lane15 = lane & 15, quad = lane >> 4;
  const int waveM = wave & 1, waveN = wave >> 1;
  const int bm = blockIdx.x * 128;
  const int bn = blockIdx.y * 128;

  v4f acc[4][4];
#pragma unroll
  for (int i = 0; i < 4; ++i)
#pragma unroll
    for (int j = 0; j < 4; ++j) acc[i][j] = (v4f){0.f, 0.f, 0.f, 0.f};

  for (int k0 = 0; k0 < CD; k0 += 32) {
#pragma unroll
    for (int p = 0; p < 2; ++p) {
      const int t = tid + p * 256;
      const int r = t >> 2, c = (t & 3) * 8;
      gld16(A + (size_t)(bm + r) * CD + k0 + c, As + t * 8);
    }
#pragma unroll
    for (int p = 0; p < 2; ++p) {
      const int t = tid + p * 256;
      const int r = t >> 2, c = (t & 3) * 8;
      gld16(Bt + (size_t)(bn + r) * CD + k0 + c, Bs + t * 8);
    }
    asm volatile("s_waitcnt vmcnt(0)" ::: "memory");
    __syncthreads();

    v8bf af[4], bfr[4];
#pragma unroll
    for (int mt = 0; mt < 4; ++mt)
      af[mt] = *(const v8bf*)(As + (waveM * 64 + mt * 16 + lane15) * 32 + quad * 8);
#pragma unroll
    for (int nt = 0; nt < 4; ++nt)
      bfr[nt] = *(const v8bf*)(Bs + (waveN * 64 + nt * 16 + lane15) * 32 + quad * 8);
#pragma unroll
    for (int mt = 0; mt < 4; ++mt)
#pragma unroll
      for (int nt = 0; nt < 4; ++nt)
        acc[mt][nt] = __builtin_amdgcn_mfma_f32_16x16x32_bf16(af[mt], bfr[nt], acc[mt][nt], 0, 0, 0);
    __syncthreads();
  }

  const float QSCALE = 0.125f * 1.4426950408889634f;  // fold D^-0.5 * log2(e)
#pragma unroll
  for (int mt = 0; mt < 4; ++mt) {
    const int rowB = bm + waveM * 64 + mt * 16 + quad * 4;
#pragma unroll
    for (int nt = 0; nt < 4; ++nt) {
      const int col = bn + waveN * 64 + nt * 16 + lane15;
      const int s = col / CD;
      const int rem = col - s * CD;
      const int h = rem >> 6, d = rem & 63;
      if (s == 2) {
        // 4 consecutive keys -> one 8B store at the PV-permuted position
        bf vp[4];
#pragma unroll
        for (int i = 0; i < 4; ++i) vp[i] = (bf)acc[mt][nt][i];
        const int pos = (rowB & ~31) + (((rowB & 15) >> 2) << 3) + (((rowB >> 4) & 1) << 2);
        *(uint2*)(Vtb + ((size_t)h * HD + d) * NT + pos) = *(const uint2*)vp;
      } else {
#pragma unroll
        for (int i = 0; i < 4; ++i) {
          const float v = acc[mt][nt][i];
          const int row = rowB + i;
          if (s == 0) Qb[((size_t)h * NT + row) * HD + d] = (bf)(v * QSCALE);
          else        Kb[((size_t)h * NT + row) * HD + d] = (bf)v;
        }
      }
    }
  }
}

// ------------- attention: block = 1 head x 64 Q rows; wave = 32-key quarter x all 64 Q rows --
// max-free softmax; P in registers; K/V double-buffered in LDS via global_load_lds with
// XOR swizzle applied on the GLOBAL source side (gld16 dest order is fixed).
__global__ __launch_bounds__(256, 2) void attn(
    const bf* __restrict__ Qb, const bf* __restrict__ Kb,
    const bf* __restrict__ Vtb, bf* __restrict__ Ob) {
  __shared__ __align__(16) char smem[65536];  // [K0 16K][V0 16K][K1 16K][V1 16K]
  float* Red = (float*)smem;                  // epilogue reuse

  // head->XCD affinity: blocks of one head land on one XCD (b%8 round-robin heuristic)
  const int b = blockIdx.x;
  int h, qt;
  if (b < 512) { h = b & 7;        qt = b >> 3; }
  else { const int bb = b - 512; h = 8 + (bb & 3); qt = bb >> 2; }
  const int q0 = qt * 64;

  const int tid = threadIdx.x;
  const int wave = tid >> 6, lane = tid & 63;
  const int lane15 = lane & 15, quad = lane >> 4;

  const bf* Kh = Kb + (size_t)h * NT * HD;
  const bf* Vh = Vtb + (size_t)h * HD * NT;

  // Q fragments for all 4 sub-tiles (B-operand: n=lane15=Q row, k=quad*8+j=dim)
  v8bf aQ[4][2];
#pragma unroll
  for (int sub = 0; sub < 4; ++sub) {
    const int qrow = q0 + sub * 16 + lane15;
    aQ[sub][0] = *(const v8bf*)(Qb + ((size_t)h * NT + qrow) * HD + quad * 8);
    aQ[sub][1] = *(const v8bf*)(Qb + ((size_t)h * NT + qrow) * HD + 32 + quad * 8);
  }

  v4f o[4][4];
#pragma unroll
  for (int sub = 0; sub < 4; ++sub)
#pragma unroll
    for (int dt = 0; dt < 4; ++dt) o[sub][dt] = (v4f){0.f, 0.f, 0.f, 0.f};
  float lsum[4] = {0.f, 0.f, 0.f, 0.f};

  // stage tile kt into buffer half `half` (0 or 1): 8 gld16, no VGPR round-trip.
  // K LDS unit (r,u) <- global K[kt+r][ (u^(r&7))*8 .. +8 )
  // V LDS unit (d,u) <- global V[d][ kt + (u^(d&15))*8 .. +8 )   (keys pre-permuted in Vtb)
  auto stage = [&](int half, int kt) {
    bf* Kdst = (bf*)(smem + half * 32768);
    bf* Vdst = (bf*)(smem + half * 32768 + 16384);
#pragma unroll
    for (int p = 0; p < 4; ++p) {
      const int L = p * 256 + tid;
      const int r = L >> 3, u = L & 7;
      gld16(Kh + (size_t)(kt + r) * HD + ((u ^ (r & 7)) << 3), Kdst + L * 8);
    }
#pragma unroll
    for (int p = 0; p < 4; ++p) {
      const int L = p * 256 + tid;
      const int d = L >> 4, u = L & 15;
      gld16(Vh + (size_t)d * NT + kt + ((u ^ (d & 15)) << 3), Vdst + L * 8);
    }
  };

  stage(0, 0);
  asm volatile("s_waitcnt vmcnt(0)" ::: "memory");
  __syncthreads();

  for (int it = 0; it < NT / 128; ++it) {
    const int half = it & 1;
    if (it + 1 < NT / 128) stage(half ^ 1, (it + 1) * 128);  // async, lands during compute

    const bf* Kbuf = (const bf*)(smem + half * 32768);
    const bf* Vbuf = (const bf*)(smem + half * 32768 + 16384);

    // S^T = K Q^T on this wave's 32 keys (2 chunks of 16) x all 64 Q rows
    v4bf aPlo[4], aPhi[4];
#pragma unroll
    for (int e = 0; e < 2; ++e) {
      const int k = (wave * 2 + e) * 16 + lane15;
      const int k7 = k & 7;
      const v8bf bk0 = *(const v8bf*)(Kbuf + k * 64 + ((quad ^ k7) << 3));
      const v8bf bk1 = *(const v8bf*)(Kbuf + k * 64 + (((quad ^ 4) ^ k7) << 3));
#pragma unroll
      for (int sub = 0; sub < 4; ++sub) {
        v4f z = (v4f){0.f, 0.f, 0.f, 0.f};
        z = __builtin_amdgcn_mfma_f32_16x16x32_bf16(bk0, aQ[sub][0], z, 0, 0, 0);
        z = __builtin_amdgcn_mfma_f32_16x16x32_bf16(bk1, aQ[sub][1], z, 0, 0, 0);
        v4bf p4;
#pragma unroll
        for (int r = 0; r < 4; ++r) {
          const float p = fexp2(z[r]);
          lsum[sub] += p;
          p4[r] = (bf)p;
        }
        if (e == 0) aPlo[sub] = p4; else aPhi[sub] = p4;
      }
    }

    // O += P V on this wave's 32 keys (x32 MFMA; A slot order == V position order)
#pragma unroll
    for (int dt = 0; dt < 4; ++dt) {
      const int d = dt * 16 + lane15;
      const v8bf bv = *(const v8bf*)(Vbuf + d * 128 + (((wave * 4 + quad) ^ lane15) << 3));
#pragma unroll
      for (int sub = 0; sub < 4; ++sub) {
        const v8bf aP8 = __builtin_shufflevector(aPlo[sub], aPhi[sub], 0, 1, 2, 3, 4, 5, 6, 7);
        o[sub][dt] = __builtin_amdgcn_mfma_f32_16x16x32_bf16(aP8, bv, o[sub][dt], 0, 0, 0);
      }
    }

    asm volatile("s_waitcnt vmcnt(0)" ::: "memory");  // next-tile loads landed
    __syncthreads();
  }

  // quad-reduce denoms: lane then holds denom partial (this wave's 32 keys) for Qrow=lane15
#pragma unroll
  for (int sub = 0; sub < 4; ++sub) {
    lsum[sub] += __shfl_xor(lsum[sub], 16, 64);
    lsum[sub] += __shfl_xor(lsum[sub], 32, 64);
  }

  // cross-wave combine, two phases of 2 subs. Region rw=wave*2+sl: 1024 f; lsum @ 8192.
#pragma unroll
  for (int sp = 0; sp < 2; ++sp) {
    __syncthreads();
#pragma unroll
    for (int sl = 0; sl < 2; ++sl) {
      const int s = sp * 2 + sl;
      float* reg = Red + (wave * 2 + sl) * 1024;
#pragma unroll
      for (int dt = 0; dt < 4; ++dt)
        *(v4f*)(reg + dt * 256 + lane15 * 16 + quad * 4) = o[s][dt];
      if (quad == 0) Red[8192 + (wave * 2 + sl) * 16 + lane15] = lsum[s];
    }
    __syncthreads();
    const int wlo = sp * 2;
    if (wave == wlo || wave == wlo + 1) {
      const int sl = wave - wlo;
      const int s = sp * 2 + sl;
      float den = 0.f;
#pragma unroll
      for (int wv = 0; wv < 4; ++wv) den += Red[8192 + (wv * 2 + sl) * 16 + lane15];
      const float linv = 1.f / den;
#pragma unroll
      for (int dt = 0; dt < 4; ++dt) {
        v4f sum = (v4f){0.f, 0.f, 0.f, 0.f};
#pragma unroll
        for (int wv = 0; wv < 4; ++wv)
          sum += *(const v4f*)(Red + (wv * 2 + sl) * 1024 + dt * 256 + lane15 * 16 + quad * 4);
#pragma unroll
        for (int i = 0; i < 4; ++i) {
          const float linv_i = __shfl(linv, quad * 4 + i, 64);
          const int row = q0 + s * 16 + quad * 4 + i;
          Ob[(size_t)row * CD + h * HD + dt * 16 + lane15] = (bf)(sum[i] * linv_i);
        }
      }
    }
  }
}

// ------------- proj GEMM: Ob[4096x768] * WpT[768x768]^T + bias -> out fp32 -------------
__global__ __launch_bounds__(256) void gemm_proj(
    const bf* __restrict__ A, const bf* __restrict__ Bt,
    const float* __restrict__ bias, float* __restrict__ out) {
  __shared__ __align__(16) bf As[128 * 32];
  __shared__ __align__(16) bf Bs[128 * 32];
  const int tid = threadIdx.x;
  const int lane = tid & 63, wave = tid >> 6;
  const int lane15 = lane & 15, quad = lane >> 4;
  const int waveM = wave & 1, waveN = wave >> 1;
  const int bm = blockIdx.x * 128;
  const int bn = blockIdx.y * 128;

  v4f acc[4][4];
#pragma unroll
  for (int i = 0; i < 4; ++i)
#pragma unroll
    for (int j = 0; j < 4; ++j) acc[i][j] = (v4f){0.f, 0.f, 0.f, 0.f};

  for (int k0 = 0; k0 < CD; k0 += 32) {
#pragma unroll
    for (int p = 0; p < 2; ++p) {
      const int t = tid + p * 256;
      const int r = t >> 2, c = (t & 3) * 8;
      gld16(A + (size_t)(bm + r) * CD + k0 + c, As + t * 8);
    }
#pragma unroll
    for (int p = 0; p < 2; ++p) {
      const int t = tid + p * 256;
      const int r = t >> 2, c = (t & 3) * 8;
      gld16(Bt + (size_t)(bn + r) * CD + k0 + c, Bs + t * 8);
    }
    asm volatile("s_waitcnt vmcnt(0)" ::: "memory");
    __syncthreads();

    v8bf af[4], bfr[4];
#pragma unroll
    for (int mt = 0; mt < 4; ++mt)
      af[mt] = *(const v8bf*)(As + (waveM * 64 + mt * 16 + lane15) * 32 + quad * 8);
#pragma unroll
    for (int nt = 0; nt < 4; ++nt)
      bfr[nt] = *(const v8bf*)(Bs + (waveN * 64 + nt * 16 + lane15) * 32 + quad * 8);
#pragma unroll
    for (int mt = 0; mt < 4; ++mt)
#pragma unroll
      for (int nt = 0; nt < 4; ++nt)
        acc[mt][nt] = __builtin_amdgcn_mfma_f32_16x16x32_bf16(af[mt], bfr[nt], acc[mt][nt], 0, 0, 0);
    __syncthreads();
  }

#pragma unroll
  for (int mt = 0; mt < 4; ++mt) {
    const int rowB = bm + waveM * 64 + mt * 16 + quad * 4;
#pragma unroll
    for (int nt = 0; nt < 4; ++nt) {
      const int col = bn + waveN * 64 + nt * 16 + lane15;
      const float bcol = bias[col];
#pragma unroll
      for (int i = 0; i < 4; ++i)
        out[(size_t)(rowB + i) * CD + col] = acc[mt][nt][i] + bcol;
    }
  }
}

extern "C" void kernel_launch(void* const* d_in, const int* in_sizes, int n_in,
                              void* d_out, int out_size, void* d_ws, size_t ws_size,
                              hipStream_t stream) {
  const float* x     = (const float*)d_in[0];   // [4096][768] fp32
  const float* wqkv  = (const float*)d_in[1];   // [768][2304] fp32
  const float* wproj = (const float*)d_in[2];   // [768][768]  fp32
  const float* bproj = (const float*)d_in[3];   // [768]       fp32
  float* out = (float*)d_out;                   // [4096][768] fp32

  bf* ws    = (bf*)d_ws;
  bf* Xb    = ws;  ws += (size_t)NT * CD;        // [4096][768] bf16
  bf* WqkvT = ws;  ws += (size_t)CQ * CD;        // [2304][768]
  bf* WpT   = ws;  ws += (size_t)CD * CD;        // [768][768]
  bf* Qb    = ws;  ws += (size_t)NH * NT * HD;   // [h][n][d], pre-scaled by 0.125*log2e
  bf* Kb    = ws;  ws += (size_t)NH * NT * HD;   // [h][n][d]
  bf* Vtb   = ws;  ws += (size_t)NH * NT * HD;   // [h][d][n], keys PV-slot-permuted per 32
  bf* Ob    = ws;  ws += (size_t)NT * CD;        // [n][h*64+d]

  prep<<<5376, 256, 0, stream>>>(x, wqkv, wproj, Xb, WqkvT, WpT);
  gemm_qkv<<<dim3(NT / 128, CQ / 128), 256, 0, stream>>>(Xb, WqkvT, Qb, Kb, Vtb);
  attn<<<768, 256, 0, stream>>>(Qb, Kb, Vtb, Ob);
  gemm_proj<<<dim3(NT / 128, CD / 128), 256, 0, stream>>>(Ob, WpT, bproj, out);
}

// Round 10
// 177.299 us; speedup vs baseline: 1.6450x; 1.0152x over previous
//
#include <hip/hip_runtime.h>
#include <hip/hip_bf16.h>

#define NT 4096   // tokens
#define CD 768    // channels
#define NH 12     // heads
#define HD 64     // head dim
#define CQ 2304   // 3*CD

typedef __bf16 bf;
typedef __bf16 v8bf __attribute__((ext_vector_type(8)));
typedef __bf16 v4bf __attribute__((ext_vector_type(4)));
typedef float  v4f  __attribute__((ext_vector_type(4)));

// async global->LDS, 16B per lane; LDS dest is wave-uniform base + lane*16
__device__ __forceinline__ void gld16(const bf* g, bf* l) {
  __builtin_amdgcn_global_load_lds(
      (__attribute__((address_space(1))) void*)g,
      (__attribute__((address_space(3))) void*)l,
      16, 0, 0);
}

__device__ __forceinline__ float fexp2(float x) {
#if defined(__HIP_DEVICE_COMPILE__)
  return __builtin_amdgcn_exp2f(x);
#else
  return x;  // host pass never executes device code
#endif
}

// ---------- merged prep: fp32->bf16 cast of x  +  transpose-cast of both weights ----------
__global__ __launch_bounds__(256) void prep(
    const float* __restrict__ x, const float* __restrict__ wqkv,
    const float* __restrict__ wproj, bf* __restrict__ Xb,
    bf* __restrict__ WqkvT, bf* __restrict__ WpT) {
  __shared__ float tile[32][33];
  const int b = blockIdx.x, tid = threadIdx.x;
  if (b < 3072) {
    const int i = b * 256 + tid;  // n4 = 786432 = 3072*256 exactly
    const float4 v = ((const float4*)x)[i];
    bf o4[4] = {(bf)v.x, (bf)v.y, (bf)v.z, (bf)v.w};
    ((ushort4*)Xb)[i] = *(const ushort4*)o4;
    return;
  }
  const float* in;
  bf* out;
  int rows, cols, c0, r0;
  if (b < 4800) {
    const int t = b - 3072;           // 72 col-blocks x 24 row-blocks
    in = wqkv; out = WqkvT; rows = CD; cols = CQ;
    c0 = (t % 72) * 32; r0 = (t / 72) * 32;
  } else {
    const int t = b - 4800;           // 24 x 24
    in = wproj; out = WpT; rows = CD; cols = CD;
    c0 = (t % 24) * 32; r0 = (t / 24) * 32;
  }
  const int tx = tid & 31, ty = tid >> 5;  // 32 x 8
#pragma unroll
  for (int j = 0; j < 32; j += 8)
    tile[ty + j][tx] = in[(size_t)(r0 + ty + j) * cols + (c0 + tx)];
  __syncthreads();
#pragma unroll
  for (int j = 0; j < 32; j += 8)
    out[(size_t)(c0 + ty + j) * rows + (r0 + tx)] = (bf)tile[tx][ty + j];
}

// ------------- QKV GEMM: Xb[4096x768] * WqkvT[2304x768]^T, double-buffered K-loop ------------
// V is written TRANSPOSED with the per-32-key PV slot permutation baked in.
__global__ __launch_bounds__(256, 3) void gemm_qkv(
    const bf* __restrict__ A, const bf* __restrict__ Bt,
    bf* __restrict__ Qb, bf* __restrict__ Kb, bf* __restrict__ Vtb) {
  __shared__ __align__(16) bf As[2][128 * 32];
  __shared__ __align__(16) bf Bs[2][128 * 32];
  const int tid = threadIdx.x;
  const int lane = tid & 63, wave = tid >> 6;
  const int lane15 = lane & 15, quad = lane >> 4;
  const int waveM = wave & 1, waveN = wave >> 1;
  const int bm = blockIdx.x * 128;
  const int bn = blockIdx.y * 128;

  v4f acc[4][4];
#pragma unroll
  for (int i = 0; i < 4; ++i)
#pragma unroll
    for (int j = 0; j < 4; ++j) acc[i][j] = (v4f){0.f, 0.f, 0.f, 0.f};

  auto stageG = [&](int half, int k0) {
#pragma unroll
    for (int p = 0; p < 2; ++p) {
      const int t = tid + p * 256;
      const int r = t >> 2, c = (t & 3) * 8;
      gld16(A + (size_t)(bm + r) * CD + k0 + c, As[half] + t * 8);
    }
#pragma unroll
    for (int p = 0; p < 2; ++p) {
      const int t = tid + p * 256;
      const int r = t >> 2, c = (t & 3) * 8;
      gld16(Bt + (size_t)(bn + r) * CD + k0 + c, Bs[half] + t * 8);
    }
  };

  stageG(0, 0);
  asm volatile("s_waitcnt vmcnt(0)" ::: "memory");
  __syncthreads();

  for (int it = 0; it < CD / 32; ++it) {
    const int half = it & 1;
    if (it + 1 < CD / 32) stageG(half ^ 1, (it + 1) * 32);  // async, lands during compute

    v8bf af[4], bfr[4];
#pragma unroll
    for (int mt = 0; mt < 4; ++mt)
      af[mt] = *(const v8bf*)(As[half] + (waveM * 64 + mt * 16 + lane15) * 32 + quad * 8);
#pragma unroll
    for (int nt = 0; nt < 4; ++nt)
      bfr[nt] = *(const v8bf*)(Bs[half] + (waveN * 64 + nt * 16 + lane15) * 32 + quad * 8);
#pragma unroll
    for (int mt = 0; mt < 4; ++mt)
#pragma unroll
      for (int nt = 0; nt < 4; ++nt)
        acc[mt][nt] = __builtin_amdgcn_mfma_f32_16x16x32_bf16(af[mt], bfr[nt], acc[mt][nt], 0, 0, 0);

    asm volatile("s_waitcnt vmcnt(0)" ::: "memory");  // next tile landed (issued pre-compute)
    __syncthreads();
  }

  const float QSCALE = 0.125f * 1.4426950408889634f;  // fold D^-0.5 * log2(e)
#pragma unroll
  for (int mt = 0; mt < 4; ++mt) {
    const int rowB = bm + waveM * 64 + mt * 16 + quad * 4;
#pragma unroll
    for (int nt = 0; nt < 4; ++nt) {
      const int col = bn + waveN * 64 + nt * 16 + lane15;
      const int s = col / CD;
      const int rem = col - s * CD;
      const int h = rem >> 6, d = rem & 63;
      if (s == 2) {
        // 4 consecutive keys -> one 8B store at the PV-permuted position
        bf vp[4];
#pragma unroll
        for (int i = 0; i < 4; ++i) vp[i] = (bf)acc[mt][nt][i];
        const int pos = (rowB & ~31) + (((rowB & 15) >> 2) << 3) + (((rowB >> 4) & 1) << 2);
        *(uint2*)(Vtb + ((size_t)h * HD + d) * NT + pos) = *(const uint2*)vp;
      } else {
#pragma unroll
        for (int i = 0; i < 4; ++i) {
          const float v = acc[mt][nt][i];
          const int row = rowB + i;
          if (s == 0) Qb[((size_t)h * NT + row) * HD + d] = (bf)(v * QSCALE);
          else        Kb[((size_t)h * NT + row) * HD + d] = (bf)v;
        }
      }
    }
  }
}

// ------------- attention: block = 1 head x 64 Q rows; wave = 32-key quarter x all 64 Q rows --
// max-free softmax; P in registers; K/V double-buffered in LDS via global_load_lds with
// XOR swizzle applied on the GLOBAL source side (gld16 dest order is fixed).
__global__ __launch_bounds__(256, 2) void attn(
    const bf* __restrict__ Qb, const bf* __restrict__ Kb,
    const bf* __restrict__ Vtb, bf* __restrict__ Ob) {
  __shared__ __align__(16) char smem[65536];  // [K0 16K][V0 16K][K1 16K][V1 16K]
  float* Red = (float*)smem;                  // epilogue reuse

  // head->XCD affinity: blocks of one head land on one XCD (b%8 round-robin heuristic)
  const int b = blockIdx.x;
  int h, qt;
  if (b < 512) { h = b & 7;        qt = b >> 3; }
  else { const int bb = b - 512; h = 8 + (bb & 3); qt = bb >> 2; }
  const int q0 = qt * 64;

  const int tid = threadIdx.x;
  const int wave = tid >> 6, lane = tid & 63;
  const int lane15 = lane & 15, quad = lane >> 4;

  const bf* Kh = Kb + (size_t)h * NT * HD;
  const bf* Vh = Vtb + (size_t)h * HD * NT;

  // Q fragments for all 4 sub-tiles (B-operand: n=lane15=Q row, k=quad*8+j=dim)
  v8bf aQ[4][2];
#pragma unroll
  for (int sub = 0; sub < 4; ++sub) {
    const int qrow = q0 + sub * 16 + lane15;
    aQ[sub][0] = *(const v8bf*)(Qb + ((size_t)h * NT + qrow) * HD + quad * 8);
    aQ[sub][1] = *(const v8bf*)(Qb + ((size_t)h * NT + qrow) * HD + 32 + quad * 8);
  }

  v4f o[4][4];
#pragma unroll
  for (int sub = 0; sub < 4; ++sub)
#pragma unroll
    for (int dt = 0; dt < 4; ++dt) o[sub][dt] = (v4f){0.f, 0.f, 0.f, 0.f};
  float lsum[4] = {0.f, 0.f, 0.f, 0.f};

  // stage tile kt into buffer half `half` (0 or 1): 8 gld16, no VGPR round-trip.
  auto stage = [&](int half, int kt) {
    bf* Kdst = (bf*)(smem + half * 32768);
    bf* Vdst = (bf*)(smem + half * 32768 + 16384);
#pragma unroll
    for (int p = 0; p < 4; ++p) {
      const int L = p * 256 + tid;
      const int r = L >> 3, u = L & 7;
      gld16(Kh + (size_t)(kt + r) * HD + ((u ^ (r & 7)) << 3), Kdst + L * 8);
    }
#pragma unroll
    for (int p = 0; p < 4; ++p) {
      const int L = p * 256 + tid;
      const int d = L >> 4, u = L & 15;
      gld16(Vh + (size_t)d * NT + kt + ((u ^ (d & 15)) << 3), Vdst + L * 8);
    }
  };

  stage(0, 0);
  asm volatile("s_waitcnt vmcnt(0)" ::: "memory");
  __syncthreads();

  for (int it = 0; it < NT / 128; ++it) {
    const int half = it & 1;
    if (it + 1 < NT / 128) stage(half ^ 1, (it + 1) * 128);  // async, lands during compute

    const bf* Kbuf = (const bf*)(smem + half * 32768);
    const bf* Vbuf = (const bf*)(smem + half * 32768 + 16384);

    // S^T = K Q^T on this wave's 32 keys (2 chunks of 16) x all 64 Q rows
    v4bf aPlo[4], aPhi[4];
#pragma unroll
    for (int e = 0; e < 2; ++e) {
      const int k = (wave * 2 + e) * 16 + lane15;
      const int k7 = k & 7;
      const v8bf bk0 = *(const v8bf*)(Kbuf + k * 64 + ((quad ^ k7) << 3));
      const v8bf bk1 = *(const v8bf*)(Kbuf + k * 64 + (((quad ^ 4) ^ k7) << 3));
#pragma unroll
      for (int sub = 0; sub < 4; ++sub) {
        v4f z = (v4f){0.f, 0.f, 0.f, 0.f};
        z = __builtin_amdgcn_mfma_f32_16x16x32_bf16(bk0, aQ[sub][0], z, 0, 0, 0);
        z = __builtin_amdgcn_mfma_f32_16x16x32_bf16(bk1, aQ[sub][1], z, 0, 0, 0);
        v4bf p4;
#pragma unroll
        for (int r = 0; r < 4; ++r) {
          const float p = fexp2(z[r]);
          lsum[sub] += p;
          p4[r] = (bf)p;
        }
        if (e == 0) aPlo[sub] = p4; else aPhi[sub] = p4;
      }
    }

    // O += P V on this wave's 32 keys (x32 MFMA; A slot order == V position order)
#pragma unroll
    for (int dt = 0; dt < 4; ++dt) {
      const int d = dt * 16 + lane15;
      const v8bf bv = *(const v8bf*)(Vbuf + d * 128 + (((wave * 4 + quad) ^ lane15) << 3));
#pragma unroll
      for (int sub = 0; sub < 4; ++sub) {
        const v8bf aP8 = __builtin_shufflevector(aPlo[sub], aPhi[sub], 0, 1, 2, 3, 4, 5, 6, 7);
        o[sub][dt] = __builtin_amdgcn_mfma_f32_16x16x32_bf16(aP8, bv, o[sub][dt], 0, 0, 0);
      }
    }

    asm volatile("s_waitcnt vmcnt(0)" ::: "memory");  // next-tile loads landed
    __syncthreads();
  }

  // quad-reduce denoms: lane then holds denom partial (this wave's 32 keys) for Qrow=lane15
#pragma unroll
  for (int sub = 0; sub < 4; ++sub) {
    lsum[sub] += __shfl_xor(lsum[sub], 16, 64);
    lsum[sub] += __shfl_xor(lsum[sub], 32, 64);
  }

  // cross-wave combine, two phases of 2 subs. Region rw=wave*2+sl: 1024 f; lsum @ 8192.
#pragma unroll
  for (int sp = 0; sp < 2; ++sp) {
    __syncthreads();
#pragma unroll
    for (int sl = 0; sl < 2; ++sl) {
      const int s = sp * 2 + sl;
      float* reg = Red + (wave * 2 + sl) * 1024;
#pragma unroll
      for (int dt = 0; dt < 4; ++dt)
        *(v4f*)(reg + dt * 256 + lane15 * 16 + quad * 4) = o[s][dt];
      if (quad == 0) Red[8192 + (wave * 2 + sl) * 16 + lane15] = lsum[s];
    }
    __syncthreads();
    const int wlo = sp * 2;
    if (wave == wlo || wave == wlo + 1) {
      const int sl = wave - wlo;
      const int s = sp * 2 + sl;
      float den = 0.f;
#pragma unroll
      for (int wv = 0; wv < 4; ++wv) den += Red[8192 + (wv * 2 + sl) * 16 + lane15];
      const float linv = 1.f / den;
#pragma unroll
      for (int dt = 0; dt < 4; ++dt) {
        v4f sum = (v4f){0.f, 0.f, 0.f, 0.f};
#pragma unroll
        for (int wv = 0; wv < 4; ++wv)
          sum += *(const v4f*)(Red + (wv * 2 + sl) * 1024 + dt * 256 + lane15 * 16 + quad * 4);
#pragma unroll
        for (int i = 0; i < 4; ++i) {
          const float linv_i = __shfl(linv, quad * 4 + i, 64);
          const int row = q0 + s * 16 + quad * 4 + i;
          Ob[(size_t)row * CD + h * HD + dt * 16 + lane15] = (bf)(sum[i] * linv_i);
        }
      }
    }
  }
}

// ------------- proj GEMM: Ob[4096x768] * WpT[768x768]^T + bias, double-buffered -------------
__global__ __launch_bounds__(256, 3) void gemm_proj(
    const bf* __restrict__ A, const bf* __restrict__ Bt,
    const float* __restrict__ bias, float* __restrict__ out) {
  __shared__ __align__(16) bf As[2][128 * 32];
  __shared__ __align__(16) bf Bs[2][128 * 32];
  const int tid = threadIdx.x;
  const int lane = tid & 63, wave = tid >> 6;
  const int lane15 = lane & 15, quad = lane >> 4;
  const int waveM = wave & 1, waveN = wave >> 1;
  const int bm = blockIdx.x * 128;
  const int bn = blockIdx.y * 128;

  v4f acc[4][4];
#pragma unroll
  for (int i = 0; i < 4; ++i)
#pragma unroll
    for (int j = 0; j < 4; ++j) acc[i][j] = (v4f){0.f, 0.f, 0.f, 0.f};

  auto stageG = [&](int half, int k0) {
#pragma unroll
    for (int p = 0; p < 2; ++p) {
      const int t = tid + p * 256;
      const int r = t >> 2, c = (t & 3) * 8;
      gld16(A + (size_t)(bm + r) * CD + k0 + c, As[half] + t * 8);
    }
#pragma unroll
    for (int p = 0; p < 2; ++p) {
      const int t = tid + p * 256;
      const int r = t >> 2, c = (t & 3) * 8;
      gld16(Bt + (size_t)(bn + r) * CD + k0 + c, Bs[half] + t * 8);
    }
  };

  stageG(0, 0);
  asm volatile("s_waitcnt vmcnt(0)" ::: "memory");
  __syncthreads();

  for (int it = 0; it < CD / 32; ++it) {
    const int half = it & 1;
    if (it + 1 < CD / 32) stageG(half ^ 1, (it + 1) * 32);

    v8bf af[4], bfr[4];
#pragma unroll
    for (int mt = 0; mt < 4; ++mt)
      af[mt] = *(const v8bf*)(As[half] + (waveM * 64 + mt * 16 + lane15) * 32 + quad * 8);
#pragma unroll
    for (int nt = 0; nt < 4; ++nt)
      bfr[nt] = *(const v8bf*)(Bs[half] + (waveN * 64 + nt * 16 + lane15) * 32 + quad * 8);
#pragma unroll
    for (int mt = 0; mt < 4; ++mt)
#pragma unroll
      for (int nt = 0; nt < 4; ++nt)
        acc[mt][nt] = __builtin_amdgcn_mfma_f32_16x16x32_bf16(af[mt], bfr[nt], acc[mt][nt], 0, 0, 0);

    asm volatile("s_waitcnt vmcnt(0)" ::: "memory");
    __syncthreads();
  }

#pragma unroll
  for (int mt = 0; mt < 4; ++mt) {
    const int rowB = bm + waveM * 64 + mt * 16 + quad * 4;
#pragma unroll
    for (int nt = 0; nt < 4; ++nt) {
      const int col = bn + waveN * 64 + nt * 16 + lane15;
      const float bcol = bias[col];
#pragma unroll
      for (int i = 0; i < 4; ++i)
        out[(size_t)(rowB + i) * CD + col] = acc[mt][nt][i] + bcol;
    }
  }
}

extern "C" void kernel_launch(void* const* d_in, const int* in_sizes, int n_in,
                              void* d_out, int out_size, void* d_ws, size_t ws_size,
                              hipStream_t stream) {
  const float* x     = (const float*)d_in[0];   // [4096][768] fp32
  const float* wqkv  = (const float*)d_in[1];   // [768][2304] fp32
  const float* wproj = (const float*)d_in[2];   // [768][768]  fp32
  const float* bproj = (const float*)d_in[3];   // [768]       fp32
  float* out = (float*)d_out;                   // [4096][768] fp32

  bf* ws    = (bf*)d_ws;
  bf* Xb    = ws;  ws += (size_t)NT * CD;        // [4096][768] bf16
  bf* WqkvT = ws;  ws += (size_t)CQ * CD;        // [2304][768]
  bf* WpT   = ws;  ws += (size_t)CD * CD;        // [768][768]
  bf* Qb    = ws;  ws += (size_t)NH * NT * HD;   // [h][n][d], pre-scaled by 0.125*log2e
  bf* Kb    = ws;  ws += (size_t)NH * NT * HD;   // [h][n][d]
  bf* Vtb   = ws;  ws += (size_t)NH * NT * HD;   // [h][d][n], keys PV-slot-permuted per 32
  bf* Ob    = ws;  ws += (size_t)NT * CD;        // [n][h*64+d]

  prep<<<5376, 256, 0, stream>>>(x, wqkv, wproj, Xb, WqkvT, WpT);
  gemm_qkv<<<dim3(NT / 128, CQ / 128), 256, 0, stream>>>(Xb, WqkvT, Qb, Kb, Vtb);
  attn<<<768, 256, 0, stream>>>(Qb, Kb, Vtb, Ob);
  gemm_proj<<<dim3(NT / 128, CD / 128), 256, 0, stream>>>(Ob, WpT, bproj, out);
}